// Round 11
// baseline (124.777 us; speedup 1.0000x reference)
//
#include <hip/hip_runtime.h>
#include <hip/hip_bf16.h>

using short8  = __attribute__((ext_vector_type(8))) short;
using short4v = __attribute__((ext_vector_type(4))) short;
using floatx4 = __attribute__((ext_vector_type(4))) float;

#define CC 192
#define CN 4096
#define NHEAD 6
#define DHEAD 32
#define NZERO (16 * NHEAD * DHEAD * DHEAD + 16 * NHEAD * DHEAD)
#define ZBLK ((NZERO + 255) / 256)
#define TBLK ((CN * 96 + 255) / 256)

__device__ __forceinline__ float bf2f(short s) {
    return __uint_as_float(((unsigned)(unsigned short)s) << 16);
}
__device__ __forceinline__ short f2bf(float f) {
    __hip_bfloat16 h = __float2bfloat16(f);
    return *(short*)&h;
}

// ---------------- kernel 0: merged setup (zero kv/km, packed rope table, w-fragments) ----------------
__global__ void k0_all(float* __restrict__ zp, unsigned* __restrict__ tabp,
                       const float* __restrict__ qkw, __hip_bfloat16* __restrict__ wfr)
{
    int bid = blockIdx.x;
    if (bid < ZBLK) {
        int i = bid * 256 + threadIdx.x;
        if (i < NZERO) zp[i] = 0.f;
    } else if (bid < ZBLK + TBLK) {
        int idx = (bid - ZBLK) * 256 + threadIdx.x;
        if (idx >= CN * 96) return;
        int n = idx / 96, c2 = idx - n * 96;
        int h = n >> 6, w = n & 63;
        int i = (c2 < 48) ? c2 : c2 - 48;
        float pos = (float)((c2 < 48) ? h : w);
        float theta = expf(-(float)i * (9.210340371976184f / 48.0f)); // ln(10000)/48
        float ang = pos * theta;
        unsigned c = (unsigned)(unsigned short)f2bf(cosf(ang));
        unsigned s = (unsigned)(unsigned short)f2bf(sinf(ang));
        tabp[idx] = c | (s << 16);
    } else {
        // wfr[((nig*6+ks)*64 + lane)*8 + j] = bf16(qkw[col][k]),
        // col = nig*16 + (lane&15), k = ks*32 + (lane>>4)*8 + j
        int tid = (bid - ZBLK - TBLK) * 256 + threadIdx.x;
        if (tid >= 24 * 6 * 64) return;
        int lane = tid & 63;
        int ks = (tid >> 6) % 6;
        int nig = tid / (6 * 64);
        int col = nig * 16 + (lane & 15);
        int k = ks * 32 + (lane >> 4) * 8;
        const float4* src = (const float4*)(qkw + (long)col * CC + k);
        float4 f0 = src[0], f1 = src[1];
        short8 s;
        s[0] = f2bf(f0.x); s[1] = f2bf(f0.y); s[2] = f2bf(f0.z); s[3] = f2bf(f0.w);
        s[4] = f2bf(f1.x); s[5] = f2bf(f1.y); s[6] = f2bf(f1.z); s[7] = f2bf(f1.w);
        *(short8*)&wfr[(long)tid * 8] = s;
    }
}

// ---------------- kernel 1: qk GEMM + elu+1 -> q,k bf16 ; also emits xbf ----------------
// M-tile 64, 512 thr (8 waves: 2M x 4N-quarters), grid 1024 -> target 3 blocks/CU.
// B reg-staged from wfr in fragment order (r7 path); epilogue via LDS transpose
// -> coalesced short8 stores. Shared LDS pool: A[64][40] + B[24][512] (K-loop)
// re-used as T[64][200] (epilogue).
#define LDSP 40
#define AOFF 0
#define BOFF (64 * LDSP)          // 2560 shorts
__global__ __launch_bounds__(512, 6)
void k1_gemm(const float* __restrict__ x, const __hip_bfloat16* __restrict__ wfr,
             const float* __restrict__ qkb,
             __hip_bfloat16* __restrict__ qws, __hip_bfloat16* __restrict__ kws,
             __hip_bfloat16* __restrict__ xbf)
{
    __shared__ __align__(16) short LDS[64 * LDSP + 24 * 512];  // 29.7 KB

    const int tid  = threadIdx.x;
    const int wid  = tid >> 6, lane = tid & 63;
    const int wm   = wid & 1, wn = wid >> 1;     // wm: M-half, wn: N-quarter
    const int lrow = lane & 15;
    const int l4   = lane >> 4;
    const int lk   = l4 * 8;
    const long rowBase = (long)blockIdx.x * 64;

    const int ar = tid >> 3, acc_c = (tid & 7) * 4;   // A-stage: 64 rows x 32 k, 4/thread

    floatx4 acc[2][6];
#pragma unroll
    for (int i = 0; i < 2; ++i)
#pragma unroll
        for (int j = 0; j < 6; ++j) acc[i][j] = (floatx4)0.f;

    for (int ks = 0; ks < 6; ++ks) {
        const int k0 = ks * 32;

        // ---- issue staging global loads before the barrier (overlap prev MFMA) ----
        short8 bstage[3];
#pragma unroll
        for (int j = 0; j < 3; ++j) {
            int s = j * 512 + tid;            // 0..1535 = nig(24) x lane(64)
            bstage[j] = *(const short8*)&wfr[((long)((s >> 6) * 6 + ks) * 64 + (s & 63)) * 8];
        }
        float4 fa = *(const float4*)(x + (rowBase + ar) * CC + k0 + acc_c);
        short4v as;
        as[0] = f2bf(fa.x); as[1] = f2bf(fa.y); as[2] = f2bf(fa.z); as[3] = f2bf(fa.w);

        if (ks) __syncthreads();              // prev-step LDS reads done

        *(short4v*)&LDS[AOFF + ar * LDSP + acc_c] = as;
        *(short4v*)&xbf[(rowBase + ar) * CC + k0 + acc_c] = as;
#pragma unroll
        for (int j = 0; j < 3; ++j) {
            int s = j * 512 + tid;
            *(short8*)&LDS[BOFF + s * 8] = bstage[j];
        }
        __syncthreads();

        // ---- compute: 12 MFMA per wave ----
        short8 a0 = *(const short8*)&LDS[AOFF + (wm * 32 + lrow) * LDSP + lk];
        short8 a1 = *(const short8*)&LDS[AOFF + (wm * 32 + 16 + lrow) * LDSP + lk];
#pragma unroll
        for (int ni = 0; ni < 6; ++ni) {
            short8 bf = *(const short8*)&LDS[BOFF + (wn * 6 + ni) * 512 + lane * 8];
            acc[0][ni] = __builtin_amdgcn_mfma_f32_16x16x32_bf16(a0, bf, acc[0][ni], 0, 0, 0);
            acc[1][ni] = __builtin_amdgcn_mfma_f32_16x16x32_bf16(a1, bf, acc[1][ni], 0, 0, 0);
        }
    }
    __syncthreads();                          // B_lds reads done; LDS pool free

    // ---- epilogue: +bias, elu+1 -> LDS transpose -> coalesced short8 stores ----
#pragma unroll
    for (int ph = 0; ph < 2; ++ph) {          // ph0: q (wn 0,1), ph1: k (wn 2,3)
        if ((wn >> 1) == ph) {
#pragma unroll
            for (int ni = 0; ni < 6; ++ni) {
                int col = (wn & 1) * 96 + ni * 16 + lrow;   // 0..191
                float bias = qkb[ph * 192 + col];
#pragma unroll
                for (int mi = 0; mi < 2; ++mi)
#pragma unroll
                    for (int r = 0; r < 4; ++r) {
                        int row = wm * 32 + mi * 16 + l4 * 4 + r;
                        float v = acc[mi][ni][r] + bias;
                        v = (v > 0.f) ? (v + 1.f) : expf(v);
                        LDS[row * 200 + col] = f2bf(v);
                    }
            }
        }
        __syncthreads();                      // transpose buffer ready
        __hip_bfloat16* dst = ph ? kws : qws;
#pragma unroll
        for (int it = 0; it < 3; ++it) {
            int slot = it * 512 + tid;        // 0..1535 = row(64) x sub(24)
            int row = slot / 24, c0 = (slot - row * 24) * 8;
            short8 v = *(const short8*)&LDS[row * 200 + c0];
            *(short8*)&dst[(rowBase + row) * CC + c0] = v;
        }
        if (ph == 0) __syncthreads();         // copy reads done before k-phase writes
    }
}

// ---------------- kernel 2: kv = (1/4096) k_rope^T v ; kmean ----------------
__global__ __launch_bounds__(256)
void k2_kv(const __hip_bfloat16* __restrict__ kws, const __hip_bfloat16* __restrict__ xbf,
           const unsigned* __restrict__ tabp, float* __restrict__ kv, float* __restrict__ kmean)
{
    int bid = blockIdx.x;
    int chunk = bid & 15;
    int hd = (bid >> 4) % NHEAD;
    int b = bid / (16 * NHEAD);
    int tid = threadIdx.x;

    __shared__ __align__(16) float kr_s[64][36];
    __shared__ __align__(16) float v_s[64][36];
    __shared__ float km_s[32];

    if (tid < 32) km_s[tid] = 0.f;

    const int e_g = tid & 31, g = tid >> 5, d4 = g * 4;
    const int krow = tid >> 2, kq = tid & 3;   // 64 rows/pass

    float acc0 = 0.f, acc1 = 0.f, acc2 = 0.f, acc3 = 0.f;
    float msum[8];
#pragma unroll
    for (int j = 0; j < 8; ++j) msum[j] = 0.f;

    const int n0 = chunk * 256;
    const long rb = (long)b * CN;

    for (int batch = 0; batch < 4; ++batch) {
        const int nb = n0 + batch * 64;
        if (batch) __syncthreads();
        {
            int r = krow;
            int n = nb + r;
            short8 kq8 = *(const short8*)&kws[(rb + n) * CC + hd * DHEAD + kq * 8];
            float kf[8];
#pragma unroll
            for (int j = 0; j < 8; ++j) { kf[j] = bf2f(kq8[j]); msum[j] += kf[j]; }
            uint4 u = *(const uint4*)&tabp[(long)n * 96 + hd * 16 + kq * 4];
            float4 t0, t1;
            t0.x = bf2f((short)(u.x & 0xffff)); t0.y = bf2f((short)(u.x >> 16));
            t0.z = bf2f((short)(u.y & 0xffff)); t0.w = bf2f((short)(u.y >> 16));
            t1.x = bf2f((short)(u.z & 0xffff)); t1.y = bf2f((short)(u.z >> 16));
            t1.z = bf2f((short)(u.w & 0xffff)); t1.w = bf2f((short)(u.w >> 16));
            float4 r0, r1;
            r0.x = kf[0]*t0.x - kf[1]*t0.y;  r0.y = kf[0]*t0.y + kf[1]*t0.x;
            r0.z = kf[2]*t0.z - kf[3]*t0.w;  r0.w = kf[2]*t0.w + kf[3]*t0.z;
            r1.x = kf[4]*t1.x - kf[5]*t1.y;  r1.y = kf[4]*t1.y + kf[5]*t1.x;
            r1.z = kf[6]*t1.z - kf[7]*t1.w;  r1.w = kf[6]*t1.w + kf[7]*t1.z;
            *(float4*)&kr_s[r][kq * 8]     = r0;
            *(float4*)&kr_s[r][kq * 8 + 4] = r1;
        }
        {
            int r = krow;
            short8 v8 = *(const short8*)&xbf[(rb + nb + r) * CC + hd * DHEAD + kq * 8];
            float4 va, vb;
            va.x = bf2f(v8[0]); va.y = bf2f(v8[1]); va.z = bf2f(v8[2]); va.w = bf2f(v8[3]);
            vb.x = bf2f(v8[4]); vb.y = bf2f(v8[5]); vb.z = bf2f(v8[6]); vb.w = bf2f(v8[7]);
            *(float4*)&v_s[r][kq * 8]     = va;
            *(float4*)&v_s[r][kq * 8 + 4] = vb;
        }
        __syncthreads();
#pragma unroll 8
        for (int r = 0; r < 64; ++r) {
            float4 k4 = *(const float4*)&kr_s[r][d4];
            float v1 = v_s[r][e_g];
            acc0 += k4.x * v1; acc1 += k4.y * v1; acc2 += k4.z * v1; acc3 += k4.w * v1;
        }
    }
    const float s = 1.f / 4096.f;
    float* kvb = kv + (long)(b * NHEAD + hd) * DHEAD * DHEAD;
    atomicAdd(&kvb[(d4 + 0) * DHEAD + e_g], acc0 * s);
    atomicAdd(&kvb[(d4 + 1) * DHEAD + e_g], acc1 * s);
    atomicAdd(&kvb[(d4 + 2) * DHEAD + e_g], acc2 * s);
    atomicAdd(&kvb[(d4 + 3) * DHEAD + e_g], acc3 * s);
    __syncthreads();
#pragma unroll
    for (int j = 0; j < 8; ++j) atomicAdd(&km_s[kq * 8 + j], msum[j]);
    __syncthreads();
    if (tid < 32) atomicAdd(&kmean[(b * NHEAD + hd) * DHEAD + tid], km_s[tid] * s);
}

// ---------------- kernel 3: out = (q_rope @ kv) * z + lepe ----------------
__global__ __launch_bounds__(256)
void k3_out(const __hip_bfloat16* __restrict__ qws, const __hip_bfloat16* __restrict__ xbf,
            const unsigned* __restrict__ tabp, const float* __restrict__ kv,
            const float* __restrict__ kmean, const float* __restrict__ lw,
            const float* __restrict__ lb, float* __restrict__ out)
{
    int raw = blockIdx.x;
    int bid = (raw & 7) * 128 + (raw >> 3);   // 8 XCDs x 128 contiguous blocks
    int b = bid >> 6, h = bid & 63;
    int tid = threadIdx.x;
    int wave = tid >> 6, lane = tid & 63, lrow = lane & 15, l4 = lane >> 4;

    __shared__ __align__(16) __hip_bfloat16 qa[64][104];        // q_rope, then attn*z
    __shared__ __align__(16) __hip_bfloat16 kvt[NHEAD][32][36]; // [hd][e][d]
    __shared__ __align__(16) float lwT[9][192];                 // [tap][ch]
    __shared__ float lb_lds[CC];
    __shared__ float km_lds[CC];
    __shared__ float zden[64][8];

    const long nbase = (long)b * CN + h * 64;

    const float* kvsrc = kv + (long)b * NHEAD * DHEAD * DHEAD;
    for (int i = tid; i < NHEAD * DHEAD * DHEAD; i += 256) {
        int hd = i >> 10, d = (i >> 5) & 31, e = i & 31;
        kvt[hd][e][d] = __float2bfloat16(kvsrc[i]);
    }
    if (tid < CC) { km_lds[tid] = kmean[b * CC + tid]; lb_lds[tid] = lb[tid]; }
    for (int i = tid; i < CC * 9; i += 256) {
        int c = i / 9, tap = i - c * 9;
        lwT[tap][c] = lw[i];
    }
    __syncthreads();

#pragma unroll
    for (int half = 0; half < 2; ++half) {
#pragma unroll
        for (int it = 0; it < 3; ++it) {
            int slot = it * 256 + tid;          // 0..767 = w(64) x sub(12)
            int w = slot / 12;
            int sub = slot - w * 12;
            int c0 = half * 96 + sub * 8;
            short8 qv = *(const short8*)&qws[(nbase + w) * CC + c0];
            float q[8];
#pragma unroll
            for (int j = 0; j < 8; ++j) q[j] = bf2f(qv[j]);
            float p = 0.f;
#pragma unroll
            for (int j = 0; j < 8; ++j) p += q[j] * km_lds[c0 + j];
            p += __shfl_xor(p, 1);
            p += __shfl_xor(p, 2);
            if ((sub & 3) == 0) zden[w][half * 3 + (sub >> 2)] = p;
            int n = h * 64 + w;
            uint4 u = *(const uint4*)&tabp[(long)n * 96 + (c0 >> 1)];
            float4 t0, t1;
            t0.x = bf2f((short)(u.x & 0xffff)); t0.y = bf2f((short)(u.x >> 16));
            t0.z = bf2f((short)(u.y & 0xffff)); t0.w = bf2f((short)(u.y >> 16));
            t1.x = bf2f((short)(u.z & 0xffff)); t1.y = bf2f((short)(u.z >> 16));
            t1.z = bf2f((short)(u.w & 0xffff)); t1.w = bf2f((short)(u.w >> 16));
            short8 qr;
            qr[0] = f2bf(q[0]*t0.x - q[1]*t0.y);  qr[1] = f2bf(q[0]*t0.y + q[1]*t0.x);
            qr[2] = f2bf(q[2]*t0.z - q[3]*t0.w);  qr[3] = f2bf(q[2]*t0.w + q[3]*t0.z);
            qr[4] = f2bf(q[4]*t1.x - q[5]*t1.y);  qr[5] = f2bf(q[4]*t1.y + q[5]*t1.x);
            qr[6] = f2bf(q[6]*t1.z - q[7]*t1.w);  qr[7] = f2bf(q[6]*t1.w + q[7]*t1.z);
            *(short8*)&qa[w][sub * 8] = qr;
        }
        __syncthreads();

        const int rt = wave;
        const int wbase = rt * 16 + l4 * 4;
#pragma unroll
        for (int hl = 0; hl < 3; ++hl) {
            int hd = half * 3 + hl;
            short8 a = *(const short8*)&qa[rt * 16 + lrow][hl * 32 + l4 * 8];
            float zv[4];
#pragma unroll
            for (int r = 0; r < 4; ++r) zv[r] = 1.f / (zden[wbase + r][hd] + 1e-6f);
#pragma unroll
            for (int nt = 0; nt < 2; ++nt) {
                short8 bfr = *(const short8*)&kvt[hd][nt * 16 + lrow][l4 * 8];
                floatx4 acc = __builtin_amdgcn_mfma_f32_16x16x32_bf16(a, bfr, (floatx4)0.f, 0, 0, 0);
                int col_l = hl * 32 + nt * 16 + lrow;
#pragma unroll
                for (int r = 0; r < 4; ++r)
                    qa[wbase + r][col_l] = __float2bfloat16(acc[r] * zv[r]);
            }
        }
        __syncthreads();

#pragma unroll
        for (int it = 0; it < 3; ++it) {
            int slot = it * 256 + tid;          // 0..767 = w(64) x g(12)
            int w = slot / 12;
            int g = slot - w * 12;
            int c0g = g * 8;
            int c0 = half * 96 + c0g;
            float vals[8];
#pragma unroll
            for (int j = 0; j < 8; ++j) vals[j] = lb_lds[c0 + j];
#pragma unroll
            for (int dy = 0; dy < 3; ++dy) {
                int hy = h + dy - 1;
                if (hy < 0 || hy > 63) continue;
                const short* base = (const short*)xbf + (((long)b * 64 + hy) * 64) * CC + c0;
#pragma unroll
                for (int dx = 0; dx < 3; ++dx) {
                    int wx = w + dx - 1;
                    if (wx < 0 || wx > 63) continue;
                    short8 xv = *(const short8*)&base[(long)wx * CC];
                    const float4* wt4 = (const float4*)&lwT[dy * 3 + dx][c0];
                    float4 wa = wt4[0], wb = wt4[1];
                    vals[0] += bf2f(xv[0]) * wa.x;  vals[1] += bf2f(xv[1]) * wa.y;
                    vals[2] += bf2f(xv[2]) * wa.z;  vals[3] += bf2f(xv[3]) * wa.w;
                    vals[4] += bf2f(xv[4]) * wb.x;  vals[5] += bf2f(xv[5]) * wb.y;
                    vals[6] += bf2f(xv[6]) * wb.z;  vals[7] += bf2f(xv[7]) * wb.w;
                }
            }
            short8 at = *(const short8*)&qa[w][c0g];
#pragma unroll
            for (int j = 0; j < 8; ++j) vals[j] += bf2f(at[j]);
            float4 o0, o1;
            o0.x = vals[0]; o0.y = vals[1]; o0.z = vals[2]; o0.w = vals[3];
            o1.x = vals[4]; o1.y = vals[5]; o1.z = vals[6]; o1.w = vals[7];
            float* op = &out[(nbase + w) * CC + c0];
            *(float4*)op = o0;
            *(float4*)(op + 4) = o1;
        }
        __syncthreads();
    }
}

extern "C" void kernel_launch(void* const* d_in, const int* in_sizes, int n_in,
                              void* d_out, int out_size, void* d_ws, size_t ws_size,
                              hipStream_t stream)
{
    const float* x   = (const float*)d_in[0];
    const float* qkw = (const float*)d_in[1];
    const float* qkb = (const float*)d_in[2];
    const float* lw  = (const float*)d_in[3];
    const float* lb  = (const float*)d_in[4];
    float* out = (float*)d_out;

    char* ws = (char*)d_ws;
    unsigned* tabp = (unsigned*)ws;            ws += (size_t)CN * 96 * 4;
    __hip_bfloat16* qws = (__hip_bfloat16*)ws; ws += (size_t)16 * CN * CC * 2;
    __hip_bfloat16* kws = (__hip_bfloat16*)ws; ws += (size_t)16 * CN * CC * 2;
    __hip_bfloat16* xbf = (__hip_bfloat16*)ws; ws += (size_t)16 * CN * CC * 2;
    __hip_bfloat16* wfr = (__hip_bfloat16*)ws; ws += (size_t)24 * 6 * 64 * 8 * 2;
    float* kv = (float*)ws;                    ws += (size_t)16 * NHEAD * DHEAD * DHEAD * 4;
    float* km = (float*)ws;                    ws += (size_t)16 * NHEAD * DHEAD * 4;

    const int wblk = (24 * 6 * 64 + 255) / 256;
    k0_all<<<ZBLK + TBLK + wblk, 256, 0, stream>>>(kv, tabp, qkw, wfr);
    k1_gemm<<<1024, 512, 0, stream>>>(x, wfr, qkb, qws, kws, xbf);
    k2_kv<<<16 * NHEAD * 16, 256, 0, stream>>>(kws, xbf, tabp, kv, km);
    k3_out<<<16 * 64, 256, 0, stream>>>(qws, xbf, tabp, kv, km, lw, lb, out);
}

// Round 12
// 117.419 us; speedup vs baseline: 1.0627x; 1.0627x over previous
//
#include <hip/hip_runtime.h>
#include <hip/hip_bf16.h>

using short8  = __attribute__((ext_vector_type(8))) short;
using floatx4 = __attribute__((ext_vector_type(4))) float;

#define CC 192
#define CN 4096
#define NHEAD 6
#define DHEAD 32
#define NZERO (16 * NHEAD * DHEAD * DHEAD + 16 * NHEAD * DHEAD)
#define ZBLK ((NZERO + 255) / 256)
#define TBLK ((CN * 96 + 255) / 256)

__device__ __forceinline__ float bf2f(short s) {
    return __uint_as_float(((unsigned)(unsigned short)s) << 16);
}
__device__ __forceinline__ short f2bf(float f) {
    __hip_bfloat16 h = __float2bfloat16(f);
    return *(short*)&h;
}

// ---------------- kernel 0: merged setup (zero kv/km, packed rope table, w-fragments) ----------------
__global__ void k0_all(float* __restrict__ zp, unsigned* __restrict__ tabp,
                       const float* __restrict__ qkw, __hip_bfloat16* __restrict__ wfr)
{
    int bid = blockIdx.x;
    if (bid < ZBLK) {
        int i = bid * 256 + threadIdx.x;
        if (i < NZERO) zp[i] = 0.f;
    } else if (bid < ZBLK + TBLK) {
        int idx = (bid - ZBLK) * 256 + threadIdx.x;
        if (idx >= CN * 96) return;
        int n = idx / 96, c2 = idx - n * 96;
        int h = n >> 6, w = n & 63;
        int i = (c2 < 48) ? c2 : c2 - 48;
        float pos = (float)((c2 < 48) ? h : w);
        float theta = expf(-(float)i * (9.210340371976184f / 48.0f)); // ln(10000)/48
        float ang = pos * theta;
        unsigned c = (unsigned)(unsigned short)f2bf(cosf(ang));
        unsigned s = (unsigned)(unsigned short)f2bf(sinf(ang));
        tabp[idx] = c | (s << 16);
    } else {
        // wfr[((nig*6+ks)*64 + lane)*8 + j] = bf16(qkw[col][k]),
        // col = nig*16 + (lane&15), k = ks*32 + (lane>>4)*8 + j
        int tid = (bid - ZBLK - TBLK) * 256 + threadIdx.x;
        if (tid >= 24 * 6 * 64) return;
        int lane = tid & 63;
        int ks = (tid >> 6) % 6;
        int nig = tid / (6 * 64);
        int col = nig * 16 + (lane & 15);
        int k = ks * 32 + (lane >> 4) * 8;
        const float4* src = (const float4*)(qkw + (long)col * CC + k);
        float4 f0 = src[0], f1 = src[1];
        short8 s;
        s[0] = f2bf(f0.x); s[1] = f2bf(f0.y); s[2] = f2bf(f0.z); s[3] = f2bf(f0.w);
        s[4] = f2bf(f1.x); s[5] = f2bf(f1.y); s[6] = f2bf(f1.z); s[7] = f2bf(f1.w);
        *(short8*)&wfr[(long)tid * 8] = s;
    }
}

// ---------------- kernel 1: qk GEMM + elu+1 -> q bf16, k_rope bf16, kmean ; emits xbf ----------------
// Round-10 champion structure (512 thr, 128-row tile, reg-staged B from wfr).
// Epilogue fusion: k-RoPE via __shfl_xor(v,1) pairing + kmean wave-reduce + atomics.
#define LDSP 40
__global__ __launch_bounds__(512)
void k1_gemm(const float* __restrict__ x, const __hip_bfloat16* __restrict__ wfr,
             const float* __restrict__ qkb, const unsigned* __restrict__ tabp,
             __hip_bfloat16* __restrict__ qws, __hip_bfloat16* __restrict__ kws,
             __hip_bfloat16* __restrict__ xbf, float* __restrict__ km)
{
    __shared__ __align__(16) __hip_bfloat16 A_lds[128 * LDSP];
    __shared__ __align__(16) __hip_bfloat16 B_lds[24 * 512];   // [nig][lane*8], one K-step

    const int tid  = threadIdx.x;
    const int wid  = tid >> 6, lane = tid & 63;
    const int wm   = wid >> 1, wn = wid & 1;
    const int lrow = lane & 15;
    const int l4   = lane >> 4;
    const int lk   = l4 * 8;
    const long rowBase = (long)blockIdx.x * 128;
    const int b       = blockIdx.x >> 5;              // 32 blocks per image
    const int nimgB   = (blockIdx.x & 31) * 128;

    const int ar = tid >> 2, acc_c = (tid & 3) * 8;   // A-stage coords

    floatx4 acc[2][12];
#pragma unroll
    for (int i = 0; i < 2; ++i)
#pragma unroll
        for (int j = 0; j < 12; ++j) acc[i][j] = (floatx4)0.f;

    for (int ks = 0; ks < 6; ++ks) {
        const int k0 = ks * 32;

        // ---- issue staging global loads before the barrier (overlap prev MFMA) ----
        short8 bstage[3];
#pragma unroll
        for (int j = 0; j < 3; ++j) {
            int s = j * 512 + tid;            // 0..1535 = nig(24) x lane(64)
            int nig = s >> 6, ln = s & 63;
            bstage[j] = *(const short8*)&wfr[((long)(nig * 6 + ks) * 64 + ln) * 8];
        }
        const float4* asrc = (const float4*)(x + (rowBase + ar) * CC + k0 + acc_c);
        float4 f0 = asrc[0], f1 = asrc[1];
        short8 as;
        as[0] = f2bf(f0.x); as[1] = f2bf(f0.y); as[2] = f2bf(f0.z); as[3] = f2bf(f0.w);
        as[4] = f2bf(f1.x); as[5] = f2bf(f1.y); as[6] = f2bf(f1.z); as[7] = f2bf(f1.w);

        if (ks) __syncthreads();              // prev-step LDS reads done

        *(short8*)&A_lds[ar * LDSP + acc_c] = as;
        *(short8*)&xbf[(rowBase + ar) * CC + k0 + acc_c] = as;
#pragma unroll
        for (int j = 0; j < 3; ++j) {
            int s = j * 512 + tid;
            *(short8*)&B_lds[s * 8] = bstage[j];
        }
        __syncthreads();

        // ---- compute: 24 MFMA per wave ----
        short8 a0 = *(const short8*)&A_lds[(wm * 32 + lrow) * LDSP + lk];
        short8 a1 = *(const short8*)&A_lds[(wm * 32 + 16 + lrow) * LDSP + lk];
#pragma unroll
        for (int ni = 0; ni < 12; ++ni) {
            short8 bf = *(const short8*)&B_lds[(wn * 12 + ni) * 512 + lane * 8];
            acc[0][ni] = __builtin_amdgcn_mfma_f32_16x16x32_bf16(a0, bf, acc[0][ni], 0, 0, 0);
            acc[1][ni] = __builtin_amdgcn_mfma_f32_16x16x32_bf16(a1, bf, acc[1][ni], 0, 0, 0);
        }
    }

    // ---- epilogue: +bias, elu+1; q straight, k fused-rope + kmean ----
    __hip_bfloat16* dstbase = wn ? kws : qws;
    const int odd = lrow & 1;
#pragma unroll
    for (int ni = 0; ni < 12; ++ni) {
        int col_l = ni * 16 + lrow;
        float bias = qkb[wn * 192 + col_l];
        if (wn == 0) {
#pragma unroll
            for (int mi = 0; mi < 2; ++mi) {
#pragma unroll
                for (int r = 0; r < 4; ++r) {
                    int rowl = wm * 32 + mi * 16 + l4 * 4 + r;
                    long rowg = rowBase + rowl;
                    float v = acc[mi][ni][r] + bias;
                    v = (v > 0.f) ? (v + 1.f) : expf(v);
                    dstbase[rowg * CC + col_l] = __float2bfloat16(v);
                }
            }
        } else {
            const int c2 = col_l >> 1;
            float kms = 0.f;
#pragma unroll
            for (int mi = 0; mi < 2; ++mi) {
#pragma unroll
                for (int r = 0; r < 4; ++r) {
                    int rowl = wm * 32 + mi * 16 + l4 * 4 + r;
                    long rowg = rowBase + rowl;
                    float v = acc[mi][ni][r] + bias;
                    v = (v > 0.f) ? (v + 1.f) : expf(v);
                    kms += v;
                    float p = __shfl_xor(v, 1);       // partner channel value, same row
                    unsigned u = tabp[(long)(nimgB + rowl) * 96 + c2];
                    float cs = bf2f((short)(u & 0xffff));
                    float sn = bf2f((short)(u >> 16));
                    float o = odd ? (p * sn + v * cs) : (v * cs - p * sn);
                    dstbase[rowg * CC + col_l] = __float2bfloat16(o);
                }
            }
            kms += __shfl_xor(kms, 16);
            kms += __shfl_xor(kms, 32);
            if (lane < 16) atomicAdd(&km[b * CC + col_l], kms * (1.f / 4096.f));
        }
    }
}

// ---------------- kernel 2: kv = (1/4096) kr^T v (kr pre-roped by k1) ----------------
__global__ __launch_bounds__(256)
void k2_kv(const __hip_bfloat16* __restrict__ kws, const __hip_bfloat16* __restrict__ xbf,
           float* __restrict__ kv)
{
    int bid = blockIdx.x;
    int chunk = bid & 15;
    int hd = (bid >> 4) % NHEAD;
    int b = bid / (16 * NHEAD);
    int tid = threadIdx.x;

    __shared__ __align__(16) float kr_s[64][36];
    __shared__ __align__(16) float v_s[64][36];

    const int e_g = tid & 31, g = tid >> 5, d4 = g * 4;
    const int krow = tid >> 2, kq = tid & 3;   // 64 rows/pass

    float acc0 = 0.f, acc1 = 0.f, acc2 = 0.f, acc3 = 0.f;

    const int n0 = chunk * 256;
    const long rb = (long)b * CN;

    for (int batch = 0; batch < 4; ++batch) {
        const int nb = n0 + batch * 64;
        if (batch) __syncthreads();
        {
            short8 k8 = *(const short8*)&kws[(rb + nb + krow) * CC + hd * DHEAD + kq * 8];
            float4 ka, kb;
            ka.x = bf2f(k8[0]); ka.y = bf2f(k8[1]); ka.z = bf2f(k8[2]); ka.w = bf2f(k8[3]);
            kb.x = bf2f(k8[4]); kb.y = bf2f(k8[5]); kb.z = bf2f(k8[6]); kb.w = bf2f(k8[7]);
            *(float4*)&kr_s[krow][kq * 8]     = ka;
            *(float4*)&kr_s[krow][kq * 8 + 4] = kb;
        }
        {
            short8 v8 = *(const short8*)&xbf[(rb + nb + krow) * CC + hd * DHEAD + kq * 8];
            float4 va, vb;
            va.x = bf2f(v8[0]); va.y = bf2f(v8[1]); va.z = bf2f(v8[2]); va.w = bf2f(v8[3]);
            vb.x = bf2f(v8[4]); vb.y = bf2f(v8[5]); vb.z = bf2f(v8[6]); vb.w = bf2f(v8[7]);
            *(float4*)&v_s[krow][kq * 8]     = va;
            *(float4*)&v_s[krow][kq * 8 + 4] = vb;
        }
        __syncthreads();
#pragma unroll 8
        for (int r = 0; r < 64; ++r) {
            float4 k4 = *(const float4*)&kr_s[r][d4];
            float v1 = v_s[r][e_g];
            acc0 += k4.x * v1; acc1 += k4.y * v1; acc2 += k4.z * v1; acc3 += k4.w * v1;
        }
    }
    const float s = 1.f / 4096.f;
    float* kvb = kv + (long)(b * NHEAD + hd) * DHEAD * DHEAD;
    atomicAdd(&kvb[(d4 + 0) * DHEAD + e_g], acc0 * s);
    atomicAdd(&kvb[(d4 + 1) * DHEAD + e_g], acc1 * s);
    atomicAdd(&kvb[(d4 + 2) * DHEAD + e_g], acc2 * s);
    atomicAdd(&kvb[(d4 + 3) * DHEAD + e_g], acc3 * s);
}

// ---------------- kernel 3: out = (q_rope @ kv) * z + lepe ----------------
__global__ __launch_bounds__(256)
void k3_out(const __hip_bfloat16* __restrict__ qws, const __hip_bfloat16* __restrict__ xbf,
            const unsigned* __restrict__ tabp, const float* __restrict__ kv,
            const float* __restrict__ kmean, const float* __restrict__ lw,
            const float* __restrict__ lb, float* __restrict__ out)
{
    int raw = blockIdx.x;
    int bid = (raw & 7) * 128 + (raw >> 3);   // 8 XCDs x 128 contiguous blocks
    int b = bid >> 6, h = bid & 63;
    int tid = threadIdx.x;
    int wave = tid >> 6, lane = tid & 63, lrow = lane & 15, l4 = lane >> 4;

    __shared__ __align__(16) __hip_bfloat16 qa[64][104];        // q_rope, then attn*z
    __shared__ __align__(16) __hip_bfloat16 kvt[NHEAD][32][36]; // [hd][e][d]
    __shared__ __align__(16) float lwT[9][192];                 // [tap][ch]
    __shared__ float lb_lds[CC];
    __shared__ float km_lds[CC];
    __shared__ float zden[64][8];

    const long nbase = (long)b * CN + h * 64;

    const float* kvsrc = kv + (long)b * NHEAD * DHEAD * DHEAD;
    for (int i = tid; i < NHEAD * DHEAD * DHEAD; i += 256) {
        int hd = i >> 10, d = (i >> 5) & 31, e = i & 31;
        kvt[hd][e][d] = __float2bfloat16(kvsrc[i]);
    }
    if (tid < CC) { km_lds[tid] = kmean[b * CC + tid]; lb_lds[tid] = lb[tid]; }
    for (int i = tid; i < CC * 9; i += 256) {
        int c = i / 9, tap = i - c * 9;
        lwT[tap][c] = lw[i];
    }
    __syncthreads();

#pragma unroll
    for (int half = 0; half < 2; ++half) {
#pragma unroll
        for (int it = 0; it < 3; ++it) {
            int slot = it * 256 + tid;          // 0..767 = w(64) x sub(12)
            int w = slot / 12;
            int sub = slot - w * 12;
            int c0 = half * 96 + sub * 8;
            short8 qv = *(const short8*)&qws[(nbase + w) * CC + c0];
            float q[8];
#pragma unroll
            for (int j = 0; j < 8; ++j) q[j] = bf2f(qv[j]);
            float p = 0.f;
#pragma unroll
            for (int j = 0; j < 8; ++j) p += q[j] * km_lds[c0 + j];
            p += __shfl_xor(p, 1);
            p += __shfl_xor(p, 2);
            if ((sub & 3) == 0) zden[w][half * 3 + (sub >> 2)] = p;
            int n = h * 64 + w;
            uint4 u = *(const uint4*)&tabp[(long)n * 96 + (c0 >> 1)];
            float4 t0, t1;
            t0.x = bf2f((short)(u.x & 0xffff)); t0.y = bf2f((short)(u.x >> 16));
            t0.z = bf2f((short)(u.y & 0xffff)); t0.w = bf2f((short)(u.y >> 16));
            t1.x = bf2f((short)(u.z & 0xffff)); t1.y = bf2f((short)(u.z >> 16));
            t1.z = bf2f((short)(u.w & 0xffff)); t1.w = bf2f((short)(u.w >> 16));
            short8 qr;
            qr[0] = f2bf(q[0]*t0.x - q[1]*t0.y);  qr[1] = f2bf(q[0]*t0.y + q[1]*t0.x);
            qr[2] = f2bf(q[2]*t0.z - q[3]*t0.w);  qr[3] = f2bf(q[2]*t0.w + q[3]*t0.z);
            qr[4] = f2bf(q[4]*t1.x - q[5]*t1.y);  qr[5] = f2bf(q[4]*t1.y + q[5]*t1.x);
            qr[6] = f2bf(q[6]*t1.z - q[7]*t1.w);  qr[7] = f2bf(q[6]*t1.w + q[7]*t1.z);
            *(short8*)&qa[w][sub * 8] = qr;
        }
        __syncthreads();

        const int rt = wave;
        const int wbase = rt * 16 + l4 * 4;
#pragma unroll
        for (int hl = 0; hl < 3; ++hl) {
            int hd = half * 3 + hl;
            short8 a = *(const short8*)&qa[rt * 16 + lrow][hl * 32 + l4 * 8];
            float zv[4];
#pragma unroll
            for (int r = 0; r < 4; ++r) zv[r] = 1.f / (zden[wbase + r][hd] + 1e-6f);
#pragma unroll
            for (int nt = 0; nt < 2; ++nt) {
                short8 bfr = *(const short8*)&kvt[hd][nt * 16 + lrow][l4 * 8];
                floatx4 acc = __builtin_amdgcn_mfma_f32_16x16x32_bf16(a, bfr, (floatx4)0.f, 0, 0, 0);
                int col_l = hl * 32 + nt * 16 + lrow;
#pragma unroll
                for (int r = 0; r < 4; ++r)
                    qa[wbase + r][col_l] = __float2bfloat16(acc[r] * zv[r]);
            }
        }
        __syncthreads();

#pragma unroll
        for (int it = 0; it < 3; ++it) {
            int slot = it * 256 + tid;          // 0..767 = w(64) x g(12)
            int w = slot / 12;
            int g = slot - w * 12;
            int c0g = g * 8;
            int c0 = half * 96 + c0g;
            float vals[8];
#pragma unroll
            for (int j = 0; j < 8; ++j) vals[j] = lb_lds[c0 + j];
#pragma unroll
            for (int dy = 0; dy < 3; ++dy) {
                int hy = h + dy - 1;
                if (hy < 0 || hy > 63) continue;
                const short* base = (const short*)xbf + (((long)b * 64 + hy) * 64) * CC + c0;
#pragma unroll
                for (int dx = 0; dx < 3; ++dx) {
                    int wx = w + dx - 1;
                    if (wx < 0 || wx > 63) continue;
                    short8 xv = *(const short8*)&base[(long)wx * CC];
                    const float4* wt4 = (const float4*)&lwT[dy * 3 + dx][c0];
                    float4 wa = wt4[0], wb = wt4[1];
                    vals[0] += bf2f(xv[0]) * wa.x;  vals[1] += bf2f(xv[1]) * wa.y;
                    vals[2] += bf2f(xv[2]) * wa.z;  vals[3] += bf2f(xv[3]) * wa.w;
                    vals[4] += bf2f(xv[4]) * wb.x;  vals[5] += bf2f(xv[5]) * wb.y;
                    vals[6] += bf2f(xv[6]) * wb.z;  vals[7] += bf2f(xv[7]) * wb.w;
                }
            }
            short8 at = *(const short8*)&qa[w][c0g];
#pragma unroll
            for (int j = 0; j < 8; ++j) vals[j] += bf2f(at[j]);
            float4 o0, o1;
            o0.x = vals[0]; o0.y = vals[1]; o0.z = vals[2]; o0.w = vals[3];
            o1.x = vals[4]; o1.y = vals[5]; o1.z = vals[6]; o1.w = vals[7];
            float* op = &out[(nbase + w) * CC + c0];
            *(float4*)op = o0;
            *(float4*)(op + 4) = o1;
        }
        __syncthreads();
    }
}

extern "C" void kernel_launch(void* const* d_in, const int* in_sizes, int n_in,
                              void* d_out, int out_size, void* d_ws, size_t ws_size,
                              hipStream_t stream)
{
    const float* x   = (const float*)d_in[0];
    const float* qkw = (const float*)d_in[1];
    const float* qkb = (const float*)d_in[2];
    const float* lw  = (const float*)d_in[3];
    const float* lb  = (const float*)d_in[4];
    float* out = (float*)d_out;

    char* ws = (char*)d_ws;
    unsigned* tabp = (unsigned*)ws;            ws += (size_t)CN * 96 * 4;
    __hip_bfloat16* qws = (__hip_bfloat16*)ws; ws += (size_t)16 * CN * CC * 2;
    __hip_bfloat16* kws = (__hip_bfloat16*)ws; ws += (size_t)16 * CN * CC * 2;
    __hip_bfloat16* xbf = (__hip_bfloat16*)ws; ws += (size_t)16 * CN * CC * 2;
    __hip_bfloat16* wfr = (__hip_bfloat16*)ws; ws += (size_t)24 * 6 * 64 * 8 * 2;
    float* kv = (float*)ws;                    ws += (size_t)16 * NHEAD * DHEAD * DHEAD * 4;
    float* km = (float*)ws;                    ws += (size_t)16 * NHEAD * DHEAD * 4;

    const int wblk = (24 * 6 * 64 + 255) / 256;
    k0_all<<<ZBLK + TBLK + wblk, 256, 0, stream>>>(kv, tabp, qkw, wfr);
    k1_gemm<<<512, 512, 0, stream>>>(x, wfr, qkb, tabp, qws, kws, xbf, km);
    k2_kv<<<16 * NHEAD * 16, 256, 0, stream>>>(kws, xbf, kv);
    k3_out<<<16 * 64, 256, 0, stream>>>(qws, xbf, tabp, kv, km, lw, lb, out);
}

// Round 13
// 115.755 us; speedup vs baseline: 1.0779x; 1.0144x over previous
//
#include <hip/hip_runtime.h>
#include <hip/hip_bf16.h>

using short8  = __attribute__((ext_vector_type(8))) short;
using floatx4 = __attribute__((ext_vector_type(4))) float;

#define CC 192
#define CN 4096
#define NHEAD 6
#define DHEAD 32
#define NZERO (16 * NHEAD * DHEAD * DHEAD + 16 * NHEAD * DHEAD)
#define ZBLK ((NZERO + 255) / 256)
#define TBLK ((CN * 96 + 255) / 256)

__device__ __forceinline__ float bf2f(short s) {
    return __uint_as_float(((unsigned)(unsigned short)s) << 16);
}
__device__ __forceinline__ short f2bf(float f) {
    __hip_bfloat16 h = __float2bfloat16(f);
    return *(short*)&h;
}

// ---------------- kernel 0: merged setup (zero kv/km, packed rope table, w-fragments) ----------------
__global__ void k0_all(float* __restrict__ zp, unsigned* __restrict__ tabp,
                       const float* __restrict__ qkw, __hip_bfloat16* __restrict__ wfr)
{
    int bid = blockIdx.x;
    if (bid < ZBLK) {
        int i = bid * 256 + threadIdx.x;
        if (i < NZERO) zp[i] = 0.f;
    } else if (bid < ZBLK + TBLK) {
        int idx = (bid - ZBLK) * 256 + threadIdx.x;
        if (idx >= CN * 96) return;
        int n = idx / 96, c2 = idx - n * 96;
        int h = n >> 6, w = n & 63;
        int i = (c2 < 48) ? c2 : c2 - 48;
        float pos = (float)((c2 < 48) ? h : w);
        float theta = expf(-(float)i * (9.210340371976184f / 48.0f)); // ln(10000)/48
        float ang = pos * theta;
        unsigned c = (unsigned)(unsigned short)f2bf(cosf(ang));
        unsigned s = (unsigned)(unsigned short)f2bf(sinf(ang));
        tabp[idx] = c | (s << 16);
    } else {
        int tid = (bid - ZBLK - TBLK) * 256 + threadIdx.x;
        if (tid >= 24 * 6 * 64) return;
        int lane = tid & 63;
        int ks = (tid >> 6) % 6;
        int nig = tid / (6 * 64);
        int col = nig * 16 + (lane & 15);
        int k = ks * 32 + (lane >> 4) * 8;
        const float4* src = (const float4*)(qkw + (long)col * CC + k);
        float4 f0 = src[0], f1 = src[1];
        short8 s;
        s[0] = f2bf(f0.x); s[1] = f2bf(f0.y); s[2] = f2bf(f0.z); s[3] = f2bf(f0.w);
        s[4] = f2bf(f1.x); s[5] = f2bf(f1.y); s[6] = f2bf(f1.z); s[7] = f2bf(f1.w);
        *(short8*)&wfr[(long)tid * 8] = s;
    }
}

// ---------------- kernel 1: qk GEMM + elu+1 -> q bf16, k_rope bf16, kmean ; emits xbf ----------------
// r10 K-loop; epilogue: q scatter (proven) + k via LDS restage -> coalesced
// rope pass (uint4 packed tab, in-register pairs) -> coalesced kws stores.
#define LDSP 40
#define BOFF 5120                 // shorts; A pool = 128*40 = 5120
__global__ __launch_bounds__(512)
void k1_gemm(const float* __restrict__ x, const __hip_bfloat16* __restrict__ wfr,
             const float* __restrict__ qkb, const unsigned* __restrict__ tabp,
             __hip_bfloat16* __restrict__ qws, __hip_bfloat16* __restrict__ kws,
             __hip_bfloat16* __restrict__ xbf, float* __restrict__ km)
{
    __shared__ __align__(16) short LDS[17408];   // A[0:5120] + B[5120:17408]; epilogue kbuf[128][104]

    const int tid  = threadIdx.x;
    const int wid  = tid >> 6, lane = tid & 63;
    const int wm   = wid >> 1, wn = wid & 1;
    const int lrow = lane & 15;
    const int l4   = lane >> 4;
    const int lk   = l4 * 8;
    const long rowBase = (long)blockIdx.x * 128;
    const int b       = blockIdx.x >> 5;              // 32 blocks per image
    const int nimgB   = (blockIdx.x & 31) * 128;

    const int ar = tid >> 2, acc_c = (tid & 3) * 8;   // A-stage coords

    floatx4 acc[2][12];
#pragma unroll
    for (int i = 0; i < 2; ++i)
#pragma unroll
        for (int j = 0; j < 12; ++j) acc[i][j] = (floatx4)0.f;

    for (int ks = 0; ks < 6; ++ks) {
        const int k0 = ks * 32;

        short8 bstage[3];
#pragma unroll
        for (int j = 0; j < 3; ++j) {
            int s = j * 512 + tid;            // 0..1535 = nig(24) x lane(64)
            int nig = s >> 6, ln = s & 63;
            bstage[j] = *(const short8*)&wfr[((long)(nig * 6 + ks) * 64 + ln) * 8];
        }
        const float4* asrc = (const float4*)(x + (rowBase + ar) * CC + k0 + acc_c);
        float4 f0 = asrc[0], f1 = asrc[1];
        short8 as;
        as[0] = f2bf(f0.x); as[1] = f2bf(f0.y); as[2] = f2bf(f0.z); as[3] = f2bf(f0.w);
        as[4] = f2bf(f1.x); as[5] = f2bf(f1.y); as[6] = f2bf(f1.z); as[7] = f2bf(f1.w);

        if (ks) __syncthreads();              // prev-step LDS reads done

        *(short8*)&LDS[ar * LDSP + acc_c] = as;
        *(short8*)&xbf[(rowBase + ar) * CC + k0 + acc_c] = as;
#pragma unroll
        for (int j = 0; j < 3; ++j) {
            int s = j * 512 + tid;
            *(short8*)&LDS[BOFF + s * 8] = bstage[j];
        }
        __syncthreads();

        short8 a0 = *(const short8*)&LDS[(wm * 32 + lrow) * LDSP + lk];
        short8 a1 = *(const short8*)&LDS[(wm * 32 + 16 + lrow) * LDSP + lk];
#pragma unroll
        for (int ni = 0; ni < 12; ++ni) {
            short8 bf = *(const short8*)&LDS[BOFF + (wn * 12 + ni) * 512 + lane * 8];
            acc[0][ni] = __builtin_amdgcn_mfma_f32_16x16x32_bf16(a0, bf, acc[0][ni], 0, 0, 0);
            acc[1][ni] = __builtin_amdgcn_mfma_f32_16x16x32_bf16(a1, bf, acc[1][ni], 0, 0, 0);
        }
    }
    __syncthreads();                          // K-loop LDS reads done; pool free

    // ---- Phase A: q scatter stores (wn==0) ; k elu -> kbuf cols 0..95 + kmean (wn==1) ----
#pragma unroll
    for (int ni = 0; ni < 12; ++ni) {
        int col_l = ni * 16 + lrow;
        float bias = qkb[wn * 192 + col_l];
        if (wn == 0) {
#pragma unroll
            for (int mi = 0; mi < 2; ++mi)
#pragma unroll
                for (int r = 0; r < 4; ++r) {
                    int rowl = wm * 32 + mi * 16 + l4 * 4 + r;
                    float v = acc[mi][ni][r] + bias;
                    v = (v > 0.f) ? (v + 1.f) : expf(v);
                    qws[(rowBase + rowl) * CC + col_l] = __float2bfloat16(v);
                }
        } else if (ni < 6) {
            float kms = 0.f;
#pragma unroll
            for (int mi = 0; mi < 2; ++mi)
#pragma unroll
                for (int r = 0; r < 4; ++r) {
                    int rowl = wm * 32 + mi * 16 + l4 * 4 + r;
                    float v = acc[mi][ni][r] + bias;
                    v = (v > 0.f) ? (v + 1.f) : expf(v);
                    kms += v;
                    LDS[rowl * 104 + col_l] = f2bf(v);
                }
            kms += __shfl_xor(kms, 16);
            kms += __shfl_xor(kms, 32);
            if (lane < 16) atomicAdd(&km[b * CC + col_l], kms * (1.f / 4096.f));
        }
    }
    __syncthreads();

    // ---- Phase B: coalesced rope pass, cols 0..95 ----
#pragma unroll
    for (int it = 0; it < 3; ++it) {
        int slot = it * 512 + tid;            // 0..1535 = row(128) x sub(12)
        int row = slot / 12, sub = slot - (slot / 12) * 12;
        short8 k8 = *(const short8*)&LDS[row * 104 + sub * 8];
        uint4 u = *(const uint4*)&tabp[(long)(nimgB + row) * 96 + sub * 4];
        short8 o;
        float e, od, cs, sn;
        e = bf2f(k8[0]); od = bf2f(k8[1]); cs = bf2f((short)(u.x & 0xffff)); sn = bf2f((short)(u.x >> 16));
        o[0] = f2bf(e * cs - od * sn); o[1] = f2bf(e * sn + od * cs);
        e = bf2f(k8[2]); od = bf2f(k8[3]); cs = bf2f((short)(u.y & 0xffff)); sn = bf2f((short)(u.y >> 16));
        o[2] = f2bf(e * cs - od * sn); o[3] = f2bf(e * sn + od * cs);
        e = bf2f(k8[4]); od = bf2f(k8[5]); cs = bf2f((short)(u.z & 0xffff)); sn = bf2f((short)(u.z >> 16));
        o[4] = f2bf(e * cs - od * sn); o[5] = f2bf(e * sn + od * cs);
        e = bf2f(k8[6]); od = bf2f(k8[7]); cs = bf2f((short)(u.w & 0xffff)); sn = bf2f((short)(u.w >> 16));
        o[6] = f2bf(e * cs - od * sn); o[7] = f2bf(e * sn + od * cs);
        *(short8*)&kws[(rowBase + row) * CC + sub * 8] = o;
    }
    __syncthreads();

    // ---- Phase C: k elu -> kbuf cols 96..191 + kmean (wn==1) ----
    if (wn == 1) {
#pragma unroll
        for (int ni = 6; ni < 12; ++ni) {
            int col_l = ni * 16 + lrow;
            float bias = qkb[192 + col_l];
            float kms = 0.f;
#pragma unroll
            for (int mi = 0; mi < 2; ++mi)
#pragma unroll
                for (int r = 0; r < 4; ++r) {
                    int rowl = wm * 32 + mi * 16 + l4 * 4 + r;
                    float v = acc[mi][ni][r] + bias;
                    v = (v > 0.f) ? (v + 1.f) : expf(v);
                    kms += v;
                    LDS[rowl * 104 + col_l - 96] = f2bf(v);
                }
            kms += __shfl_xor(kms, 16);
            kms += __shfl_xor(kms, 32);
            if (lane < 16) atomicAdd(&km[b * CC + col_l], kms * (1.f / 4096.f));
        }
    }
    __syncthreads();

    // ---- Phase D: coalesced rope pass, cols 96..191 ----
#pragma unroll
    for (int it = 0; it < 3; ++it) {
        int slot = it * 512 + tid;
        int row = slot / 12, sub = slot - (slot / 12) * 12;
        short8 k8 = *(const short8*)&LDS[row * 104 + sub * 8];
        uint4 u = *(const uint4*)&tabp[(long)(nimgB + row) * 96 + 48 + sub * 4];
        short8 o;
        float e, od, cs, sn;
        e = bf2f(k8[0]); od = bf2f(k8[1]); cs = bf2f((short)(u.x & 0xffff)); sn = bf2f((short)(u.x >> 16));
        o[0] = f2bf(e * cs - od * sn); o[1] = f2bf(e * sn + od * cs);
        e = bf2f(k8[2]); od = bf2f(k8[3]); cs = bf2f((short)(u.y & 0xffff)); sn = bf2f((short)(u.y >> 16));
        o[2] = f2bf(e * cs - od * sn); o[3] = f2bf(e * sn + od * cs);
        e = bf2f(k8[4]); od = bf2f(k8[5]); cs = bf2f((short)(u.z & 0xffff)); sn = bf2f((short)(u.z >> 16));
        o[4] = f2bf(e * cs - od * sn); o[5] = f2bf(e * sn + od * cs);
        e = bf2f(k8[6]); od = bf2f(k8[7]); cs = bf2f((short)(u.w & 0xffff)); sn = bf2f((short)(u.w >> 16));
        o[6] = f2bf(e * cs - od * sn); o[7] = f2bf(e * sn + od * cs);
        *(short8*)&kws[(rowBase + row) * CC + 96 + sub * 8] = o;
    }
}

// ---------------- kernel 2: kv = (1/4096) kr^T v (kr pre-roped by k1) ----------------
__global__ __launch_bounds__(256)
void k2_kv(const __hip_bfloat16* __restrict__ kws, const __hip_bfloat16* __restrict__ xbf,
           float* __restrict__ kv)
{
    int bid = blockIdx.x;
    int chunk = bid & 15;
    int hd = (bid >> 4) % NHEAD;
    int b = bid / (16 * NHEAD);
    int tid = threadIdx.x;

    __shared__ __align__(16) float kr_s[64][36];
    __shared__ __align__(16) float v_s[64][36];

    const int e_g = tid & 31, g = tid >> 5, d4 = g * 4;
    const int krow = tid >> 2, kq = tid & 3;   // 64 rows/pass

    float acc0 = 0.f, acc1 = 0.f, acc2 = 0.f, acc3 = 0.f;

    const int n0 = chunk * 256;
    const long rb = (long)b * CN;

    for (int batch = 0; batch < 4; ++batch) {
        const int nb = n0 + batch * 64;
        if (batch) __syncthreads();
        {
            short8 k8 = *(const short8*)&kws[(rb + nb + krow) * CC + hd * DHEAD + kq * 8];
            float4 ka, kb;
            ka.x = bf2f(k8[0]); ka.y = bf2f(k8[1]); ka.z = bf2f(k8[2]); ka.w = bf2f(k8[3]);
            kb.x = bf2f(k8[4]); kb.y = bf2f(k8[5]); kb.z = bf2f(k8[6]); kb.w = bf2f(k8[7]);
            *(float4*)&kr_s[krow][kq * 8]     = ka;
            *(float4*)&kr_s[krow][kq * 8 + 4] = kb;
        }
        {
            short8 v8 = *(const short8*)&xbf[(rb + nb + krow) * CC + hd * DHEAD + kq * 8];
            float4 va, vb;
            va.x = bf2f(v8[0]); va.y = bf2f(v8[1]); va.z = bf2f(v8[2]); va.w = bf2f(v8[3]);
            vb.x = bf2f(v8[4]); vb.y = bf2f(v8[5]); vb.z = bf2f(v8[6]); vb.w = bf2f(v8[7]);
            *(float4*)&v_s[krow][kq * 8]     = va;
            *(float4*)&v_s[krow][kq * 8 + 4] = vb;
        }
        __syncthreads();
#pragma unroll 8
        for (int r = 0; r < 64; ++r) {
            float4 k4 = *(const float4*)&kr_s[r][d4];
            float v1 = v_s[r][e_g];
            acc0 += k4.x * v1; acc1 += k4.y * v1; acc2 += k4.z * v1; acc3 += k4.w * v1;
        }
    }
    const float s = 1.f / 4096.f;
    float* kvb = kv + (long)(b * NHEAD + hd) * DHEAD * DHEAD;
    atomicAdd(&kvb[(d4 + 0) * DHEAD + e_g], acc0 * s);
    atomicAdd(&kvb[(d4 + 1) * DHEAD + e_g], acc1 * s);
    atomicAdd(&kvb[(d4 + 2) * DHEAD + e_g], acc2 * s);
    atomicAdd(&kvb[(d4 + 3) * DHEAD + e_g], acc3 * s);
}

// ---------------- kernel 3: out = (q_rope @ kv) * z + lepe ----------------
__global__ __launch_bounds__(256)
void k3_out(const __hip_bfloat16* __restrict__ qws, const __hip_bfloat16* __restrict__ xbf,
            const unsigned* __restrict__ tabp, const float* __restrict__ kv,
            const float* __restrict__ kmean, const float* __restrict__ lw,
            const float* __restrict__ lb, float* __restrict__ out)
{
    int raw = blockIdx.x;
    int bid = (raw & 7) * 128 + (raw >> 3);   // 8 XCDs x 128 contiguous blocks
    int b = bid >> 6, h = bid & 63;
    int tid = threadIdx.x;
    int wave = tid >> 6, lane = tid & 63, lrow = lane & 15, l4 = lane >> 4;

    __shared__ __align__(16) __hip_bfloat16 qa[64][104];        // q_rope, then attn*z
    __shared__ __align__(16) __hip_bfloat16 kvt[NHEAD][32][36]; // [hd][e][d]
    __shared__ __align__(16) float lwT[9][192];                 // [tap][ch]
    __shared__ float lb_lds[CC];
    __shared__ float km_lds[CC];
    __shared__ float zden[64][8];

    const long nbase = (long)b * CN + h * 64;

    const float* kvsrc = kv + (long)b * NHEAD * DHEAD * DHEAD;
    for (int i = tid; i < NHEAD * DHEAD * DHEAD; i += 256) {
        int hd = i >> 10, d = (i >> 5) & 31, e = i & 31;
        kvt[hd][e][d] = __float2bfloat16(kvsrc[i]);
    }
    if (tid < CC) { km_lds[tid] = kmean[b * CC + tid]; lb_lds[tid] = lb[tid]; }
    for (int i = tid; i < CC * 9; i += 256) {
        int c = i / 9, tap = i - c * 9;
        lwT[tap][c] = lw[i];
    }
    __syncthreads();

#pragma unroll
    for (int half = 0; half < 2; ++half) {
#pragma unroll
        for (int it = 0; it < 3; ++it) {
            int slot = it * 256 + tid;          // 0..767 = w(64) x sub(12)
            int w = slot / 12;
            int sub = slot - w * 12;
            int c0 = half * 96 + sub * 8;
            short8 qv = *(const short8*)&qws[(nbase + w) * CC + c0];
            float q[8];
#pragma unroll
            for (int j = 0; j < 8; ++j) q[j] = bf2f(qv[j]);
            float p = 0.f;
#pragma unroll
            for (int j = 0; j < 8; ++j) p += q[j] * km_lds[c0 + j];
            p += __shfl_xor(p, 1);
            p += __shfl_xor(p, 2);
            if ((sub & 3) == 0) zden[w][half * 3 + (sub >> 2)] = p;
            int n = h * 64 + w;
            uint4 u = *(const uint4*)&tabp[(long)n * 96 + (c0 >> 1)];
            float4 t0, t1;
            t0.x = bf2f((short)(u.x & 0xffff)); t0.y = bf2f((short)(u.x >> 16));
            t0.z = bf2f((short)(u.y & 0xffff)); t0.w = bf2f((short)(u.y >> 16));
            t1.x = bf2f((short)(u.z & 0xffff)); t1.y = bf2f((short)(u.z >> 16));
            t1.z = bf2f((short)(u.w & 0xffff)); t1.w = bf2f((short)(u.w >> 16));
            short8 qr;
            qr[0] = f2bf(q[0]*t0.x - q[1]*t0.y);  qr[1] = f2bf(q[0]*t0.y + q[1]*t0.x);
            qr[2] = f2bf(q[2]*t0.z - q[3]*t0.w);  qr[3] = f2bf(q[2]*t0.w + q[3]*t0.z);
            qr[4] = f2bf(q[4]*t1.x - q[5]*t1.y);  qr[5] = f2bf(q[4]*t1.y + q[5]*t1.x);
            qr[6] = f2bf(q[6]*t1.z - q[7]*t1.w);  qr[7] = f2bf(q[6]*t1.w + q[7]*t1.z);
            *(short8*)&qa[w][sub * 8] = qr;
        }
        __syncthreads();

        const int rt = wave;
        const int wbase = rt * 16 + l4 * 4;
#pragma unroll
        for (int hl = 0; hl < 3; ++hl) {
            int hd = half * 3 + hl;
            short8 a = *(const short8*)&qa[rt * 16 + lrow][hl * 32 + l4 * 8];
            float zv[4];
#pragma unroll
            for (int r = 0; r < 4; ++r) zv[r] = 1.f / (zden[wbase + r][hd] + 1e-6f);
#pragma unroll
            for (int nt = 0; nt < 2; ++nt) {
                short8 bfr = *(const short8*)&kvt[hd][nt * 16 + lrow][l4 * 8];
                floatx4 acc = __builtin_amdgcn_mfma_f32_16x16x32_bf16(a, bfr, (floatx4)0.f, 0, 0, 0);
                int col_l = hl * 32 + nt * 16 + lrow;
#pragma unroll
                for (int r = 0; r < 4; ++r)
                    qa[wbase + r][col_l] = __float2bfloat16(acc[r] * zv[r]);
            }
        }
        __syncthreads();

#pragma unroll
        for (int it = 0; it < 3; ++it) {
            int slot = it * 256 + tid;          // 0..767 = w(64) x g(12)
            int w = slot / 12;
            int g = slot - w * 12;
            int c0g = g * 8;
            int c0 = half * 96 + c0g;
            float vals[8];
#pragma unroll
            for (int j = 0; j < 8; ++j) vals[j] = lb_lds[c0 + j];
#pragma unroll
            for (int dy = 0; dy < 3; ++dy) {
                int hy = h + dy - 1;
                if (hy < 0 || hy > 63) continue;
                const short* base = (const short*)xbf + (((long)b * 64 + hy) * 64) * CC + c0;
#pragma unroll
                for (int dx = 0; dx < 3; ++dx) {
                    int wx = w + dx - 1;
                    if (wx < 0 || wx > 63) continue;
                    short8 xv = *(const short8*)&base[(long)wx * CC];
                    const float4* wt4 = (const float4*)&lwT[dy * 3 + dx][c0];
                    float4 wa = wt4[0], wb = wt4[1];
                    vals[0] += bf2f(xv[0]) * wa.x;  vals[1] += bf2f(xv[1]) * wa.y;
                    vals[2] += bf2f(xv[2]) * wa.z;  vals[3] += bf2f(xv[3]) * wa.w;
                    vals[4] += bf2f(xv[4]) * wb.x;  vals[5] += bf2f(xv[5]) * wb.y;
                    vals[6] += bf2f(xv[6]) * wb.z;  vals[7] += bf2f(xv[7]) * wb.w;
                }
            }
            short8 at = *(const short8*)&qa[w][c0g];
#pragma unroll
            for (int j = 0; j < 8; ++j) vals[j] += bf2f(at[j]);
            float4 o0, o1;
            o0.x = vals[0]; o0.y = vals[1]; o0.z = vals[2]; o0.w = vals[3];
            o1.x = vals[4]; o1.y = vals[5]; o1.z = vals[6]; o1.w = vals[7];
            float* op = &out[(nbase + w) * CC + c0];
            *(float4*)op = o0;
            *(float4*)(op + 4) = o1;
        }
        __syncthreads();
    }
}

extern "C" void kernel_launch(void* const* d_in, const int* in_sizes, int n_in,
                              void* d_out, int out_size, void* d_ws, size_t ws_size,
                              hipStream_t stream)
{
    const float* x   = (const float*)d_in[0];
    const float* qkw = (const float*)d_in[1];
    const float* qkb = (const float*)d_in[2];
    const float* lw  = (const float*)d_in[3];
    const float* lb  = (const float*)d_in[4];
    float* out = (float*)d_out;

    char* ws = (char*)d_ws;
    unsigned* tabp = (unsigned*)ws;            ws += (size_t)CN * 96 * 4;
    __hip_bfloat16* qws = (__hip_bfloat16*)ws; ws += (size_t)16 * CN * CC * 2;
    __hip_bfloat16* kws = (__hip_bfloat16*)ws; ws += (size_t)16 * CN * CC * 2;
    __hip_bfloat16* xbf = (__hip_bfloat16*)ws; ws += (size_t)16 * CN * CC * 2;
    __hip_bfloat16* wfr = (__hip_bfloat16*)ws; ws += (size_t)24 * 6 * 64 * 8 * 2;
    float* kv = (float*)ws;                    ws += (size_t)16 * NHEAD * DHEAD * DHEAD * 4;
    float* km = (float*)ws;                    ws += (size_t)16 * NHEAD * DHEAD * 4;

    const int wblk = (24 * 6 * 64 + 255) / 256;
    k0_all<<<ZBLK + TBLK + wblk, 256, 0, stream>>>(kv, tabp, qkw, wfr);
    k1_gemm<<<512, 512, 0, stream>>>(x, wfr, qkb, tabp, qws, kws, xbf, km);
    k2_kv<<<16 * NHEAD * 16, 256, 0, stream>>>(kws, xbf, kv);
    k3_out<<<16 * 64, 256, 0, stream>>>(qws, xbf, tabp, kv, km, lw, lb, out);
}